// Round 5
// baseline (1040.646 us; speedup 1.0000x reference)
//
#include <hip/hip_runtime.h>
#include <math.h>

#define F 256
#define KMIX 5
#define RECB 640   // node record: 512 B bf16 xm + 32 B mask bits + 96 B pad

typedef __attribute__((ext_vector_type(8))) short bf16x8;
typedef __attribute__((ext_vector_type(4))) float f32x4;

__device__ __forceinline__ float bf2f(unsigned short u) {
  union { unsigned int i; float f; } v; v.i = ((unsigned int)u) << 16; return v.f;
}
__device__ __forceinline__ float asf(unsigned int u) {
  union { unsigned int i; float f; } v; v.i = u; return v.f;
}
__device__ __forceinline__ unsigned short f2bf(float f) {
  union { float f; unsigned int i; } v; v.f = f;
  unsigned int u = v.i;
  unsigned int r = (u + 0x7fffu + ((u >> 16) & 1u)) >> 16;
  return (unsigned short)r;
}

__device__ __forceinline__ f32x4 MFMA(bf16x8 a, bf16x8 b, f32x4 c) {
  return __builtin_amdgcn_mfma_f32_16x16x32_bf16(a, b, c, 0, 0, 0);
}

// Fast E[relu(N(mu,sigma))]: 0.5*mu + 0.5*(mu^2+c1*sig)*rsqrt(mu^2+2*c1*sig), c1=4/pi.
// Exact at w=0 and asymptotes; max abs err ~0.025*sqrt(sig). sigma==0 -> max(mu,0).
__device__ __forceinline__ float ex_relu_fast(float mu, float sig) {
  const float c1 = 1.2732395447f;
  const float c2 = 2.5464790895f;
  float t = mu * mu;
  float u = t + c1 * sig;
  float v = t + c2 * sig + 1e-20f;
  float r = __builtin_amdgcn_rsqf(v);
  return 0.5f * mu + 0.5f * u * r;
}

__global__ void kzero(unsigned int* p, long long n) {
  long long i = (long long)blockIdx.x * blockDim.x + threadIdx.x;
  long long stride = (long long)gridDim.x * blockDim.x;
  for (; i < n; i += stride) p[i] = 0u;
}

// ivar[k][f] = exp(-logvars[k][f])
__global__ __launch_bounds__(256) void k_tab(const float* __restrict__ logvars,
                                             float* __restrict__ ivar) {
  int i = blockIdx.x * 256 + threadIdx.x;
  if (i < KMIX * F) ivar[i] = __expf(-logvars[i]);
}

// Per-node: record = [bf16 xm | bit mask], gamma = softmax_k(logp - 0.5*sum diff2)
__global__ __launch_bounds__(256) void k_prep(
    const float* __restrict__ x, const int* __restrict__ mask,
    const float* __restrict__ logp, const float* __restrict__ means,
    const float* __restrict__ ivar,
    unsigned char* __restrict__ rec, float* __restrict__ gamma, int Npad) {
  int n = blockIdx.x;
  int f = threadIdx.x;
  int idx = n * F + f;
  float xv = x[idx];
  int m = mask[idx];
  unsigned char* rn = rec + (size_t)n * RECB;
  ((unsigned short*)rn)[f] = m ? (unsigned short)0 : f2bf(xv);
  int wave = threadIdx.x >> 6;
  int lane = threadIdx.x & 63;
  unsigned long long bal = __ballot(m != 0);
  if (lane == 0) *(unsigned long long*)(rn + 512 + wave * 8) = bal;
  float cb[KMIX];
#pragma unroll
  for (int k = 0; k < KMIX; ++k) {
    float d = xv - means[k * F + f];
    cb[k] = m ? 0.0f : d * d * ivar[k * F + f];
  }
  __shared__ float red[KMIX][4];
#pragma unroll
  for (int k = 0; k < KMIX; ++k) {
    float c = cb[k];
    for (int off = 32; off > 0; off >>= 1) c += __shfl_down(c, off, 64);
    if (lane == 0) red[k][wave] = c;
  }
  __syncthreads();
  if (threadIdx.x == 0) {
    float lg[KMIX], mx = -1e30f;
#pragma unroll
    for (int k = 0; k < KMIX; ++k) {
      float tot = red[k][0] + red[k][1] + red[k][2] + red[k][3];
      lg[k] = logp[k] - 0.5f * tot;
      mx = fmaxf(mx, lg[k]);
    }
    float den = 0.0f, e[KMIX];
#pragma unroll
    for (int k = 0; k < KMIX; ++k) { e[k] = __expf(lg[k] - mx); den += e[k]; }
    float inv = 1.0f / den;
#pragma unroll
    for (int k = 0; k < KMIX; ++k) gamma[k * Npad + n] = e[k] * inv;
  }
}

__global__ void k_count(const int* __restrict__ edges, int* __restrict__ deg, int E) {
  int i = blockIdx.x * blockDim.x + threadIdx.x;
  if (i < E) atomicAdd(&deg[edges[E + i]], 1);
}

__global__ __launch_bounds__(1024) void k_scan(const int* __restrict__ deg,
                                               int* __restrict__ offsets,
                                               int* __restrict__ cursor, int N) {
  __shared__ int sums[1024];
  int t = threadIdx.x;
  int CH = (N + 1023) >> 10;
  int base = t * CH;
  int s = 0;
  for (int i = 0; i < CH; ++i) { int j = base + i; if (j < N) s += deg[j]; }
  sums[t] = s;
  __syncthreads();
  for (int off = 1; off < 1024; off <<= 1) {
    int v = (t >= off) ? sums[t - off] : 0;
    __syncthreads();
    sums[t] += v;
    __syncthreads();
  }
  int run = (t == 0) ? 0 : sums[t - 1];
  for (int i = 0; i < CH; ++i) {
    int j = base + i;
    if (j < N) { offsets[j] = run; cursor[j] = run; run += deg[j]; }
  }
  if (t == 1023) offsets[N] = sums[1023];
}

__global__ void k_fill(const int* __restrict__ edges, int* __restrict__ cursor,
                       int* __restrict__ srclist, int E) {
  int i = blockIdx.x * blockDim.x + threadIdx.x;
  if (i < E) {
    int d = edges[E + i];
    int pos = atomicAdd(&cursor[d], 1);
    srclist[pos] = edges[i];
  }
}

// One wave per node, 16 nodes/block. Half-waves process neighbor pairs:
// lane<32 -> even neighbor, lane>=32 -> odd; each lane covers 8 features (16 B).
__global__ __launch_bounds__(1024) void k_gather(
    const unsigned char* __restrict__ rec,
    const int* __restrict__ offsets, const int* __restrict__ srclist,
    unsigned short* __restrict__ xs_pack, unsigned short* __restrict__ sm_pack,
    float* __restrict__ degp1) {
  __shared__ float xs_l[16][260];
  __shared__ float sm_l[16][260];
  int tile = blockIdx.x;
  int wave = threadIdx.x >> 6, lane = threadIdx.x & 63;
  int half = lane >> 5, hl = lane & 31;
  int n = tile * 16 + wave;
  const int xoff = hl * 16;
  const int woff = 512 + (hl & 28);
  const int bsh = (hl & 3) * 8;
  float fa0 = 0.f, fa1 = 0.f, fa2 = 0.f, fa3 = 0.f, fa4 = 0.f, fa5 = 0.f, fa6 = 0.f, fa7 = 0.f;
  unsigned int mac0 = 0u, mac1 = 0u;

#define ACCUM(XV, MW)                                                        \
  {                                                                          \
    fa0 += asf((XV).x << 16); fa1 += asf((XV).x & 0xFFFF0000u);              \
    fa2 += asf((XV).y << 16); fa3 += asf((XV).y & 0xFFFF0000u);              \
    fa4 += asf((XV).z << 16); fa5 += asf((XV).z & 0xFFFF0000u);              \
    fa6 += asf((XV).w << 16); fa7 += asf((XV).w & 0xFFFF0000u);              \
    unsigned int w8 = ((MW) >> bsh) & 0xFFu;                                 \
    unsigned int lo = w8 & 0xFu, hi = w8 >> 4;                               \
    mac0 += (lo | (lo << 7) | (lo << 14) | (lo << 21)) & 0x01010101u;        \
    mac1 += (hi | (hi << 7) | (hi << 14) | (hi << 21)) & 0x01010101u;        \
  }

  if (half == 0) {  // self term
    const unsigned char* rs = rec + (size_t)n * RECB;
    uint4 xv = *(const uint4*)(rs + xoff);
    unsigned int mw = *(const unsigned int*)(rs + woff);
    ACCUM(xv, mw);
  }
  int s0 = offsets[n], s1 = offsets[n + 1];
  int count = s1 - s0, pairs = count >> 1;
  int p = 0;
  for (; p + 4 <= pairs; p += 4) {
    int i0 = s0 + 2 * p + half;
    int ia = srclist[i0], ib = srclist[i0 + 2], ic = srclist[i0 + 4], id = srclist[i0 + 6];
    const unsigned char* ra = rec + (size_t)ia * RECB;
    const unsigned char* rb = rec + (size_t)ib * RECB;
    const unsigned char* rc = rec + (size_t)ic * RECB;
    const unsigned char* rd = rec + (size_t)id * RECB;
    uint4 xa = *(const uint4*)(ra + xoff);
    uint4 xb = *(const uint4*)(rb + xoff);
    uint4 xc = *(const uint4*)(rc + xoff);
    uint4 xd = *(const uint4*)(rd + xoff);
    unsigned int wa = *(const unsigned int*)(ra + woff);
    unsigned int wb = *(const unsigned int*)(rb + woff);
    unsigned int wc = *(const unsigned int*)(rc + woff);
    unsigned int wd = *(const unsigned int*)(rd + woff);
    ACCUM(xa, wa); ACCUM(xb, wb); ACCUM(xc, wc); ACCUM(xd, wd);
  }
  for (; p < pairs; ++p) {
    int i0 = s0 + 2 * p + half;
    const unsigned char* rs = rec + (size_t)srclist[i0] * RECB;
    uint4 xv = *(const uint4*)(rs + xoff);
    unsigned int mw = *(const unsigned int*)(rs + woff);
    ACCUM(xv, mw);
  }
  if ((count & 1) && half) {  // odd tail -> high half only
    const unsigned char* rs = rec + (size_t)srclist[s1 - 1] * RECB;
    uint4 xv = *(const uint4*)(rs + xoff);
    unsigned int mw = *(const unsigned int*)(rs + woff);
    ACCUM(xv, mw);
  }
#undef ACCUM
  // combine halves
  fa0 += __shfl_xor(fa0, 32, 64); fa1 += __shfl_xor(fa1, 32, 64);
  fa2 += __shfl_xor(fa2, 32, 64); fa3 += __shfl_xor(fa3, 32, 64);
  fa4 += __shfl_xor(fa4, 32, 64); fa5 += __shfl_xor(fa5, 32, 64);
  fa6 += __shfl_xor(fa6, 32, 64); fa7 += __shfl_xor(fa7, 32, 64);
  mac0 += __shfl_xor(mac0, 32, 64);
  mac1 += __shfl_xor(mac1, 32, 64);
  if (half == 0) {
    float4 v0 = {fa0, fa1, fa2, fa3};
    float4 v1 = {fa4, fa5, fa6, fa7};
    *(float4*)&xs_l[wave][hl * 8] = v0;
    *(float4*)&xs_l[wave][hl * 8 + 4] = v1;
    float4 m0 = {(float)(mac0 & 0xFFu), (float)((mac0 >> 8) & 0xFFu),
                 (float)((mac0 >> 16) & 0xFFu), (float)(mac0 >> 24)};
    float4 m1 = {(float)(mac1 & 0xFFu), (float)((mac1 >> 8) & 0xFFu),
                 (float)((mac1 >> 16) & 0xFFu), (float)(mac1 >> 24)};
    *(float4*)&sm_l[wave][hl * 8] = m0;
    *(float4*)&sm_l[wave][hl * 8 + 4] = m1;
  }
  if (lane == 0) degp1[n] = (float)(count + 1);
  __syncthreads();
  if (threadIdx.x < 512) {
    int slot = threadIdx.x;
    int kt = slot >> 6, l = slot & 63;
    int r = l & 15, q = l >> 4;
    int fbase = kt * 32 + q * 8;
    bf16x8 vx, vs;
#pragma unroll
    for (int j = 0; j < 8; ++j) {
      vx[j] = (short)f2bf(xs_l[r][fbase + j]);
      vs[j] = (short)f2bf(sm_l[r][fbase + j]);
    }
    long long po = ((long long)tile * 8 + kt) * 64 + l;
    ((bf16x8*)xs_pack)[po] = vx;
    ((bf16x8*)sm_pack)[po] = vs;
  }
}

// Pack 11 B-matrices in MFMA B-fragment order (m=0: W; 1..5: means_k*W; 6..10: var_k*W^2)
__global__ __launch_bounds__(64) void k_bpack(
    const float* __restrict__ weight, const float* __restrict__ means,
    const float* __restrict__ logvars, unsigned short* __restrict__ bpack) {
  int bid = blockIdx.x;
  int kt = bid & 7, ot = (bid >> 3) & 15, m = bid >> 7;
  int l = threadIdx.x;
  int r = l & 15, q = l >> 4;
  int o = ot * 16 + r;
  bf16x8 v;
#pragma unroll
  for (int j = 0; j < 8; ++j) {
    int f = kt * 32 + q * 8 + j;
    float wv = weight[f * F + o];
    float val;
    if (m == 0) val = wv;
    else if (m <= 5) val = means[(m - 1) * F + f] * wv;
    else val = __expf(logvars[(m - 6) * F + f]) * wv * wv;
    v[j] = (short)f2bf(val);
  }
  ((bf16x8*)bpack)[((long long)(m * 16 + ot) * 8 + kt) * 64 + l] = v;
}

// Fused GEMM + ex_relu + gamma-weighted k-reduction.
// 1-D swizzled grid: L&7 = XCD slot; all 4 bo-blocks of one bm land on the same XCD.
// Depth-2 register prefetch of B fragments across the unrolled kt loop.
__global__ __launch_bounds__(256, 2) void k_gemm(
    const unsigned short* __restrict__ xs_pack, const unsigned short* __restrict__ sm_pack,
    const unsigned short* __restrict__ bpack, const float* __restrict__ degp1,
    const float* __restrict__ gamma, const float* __restrict__ bias,
    float* __restrict__ out, int N, int Npad, int MB) {
  int L = blockIdx.x;
  int bm = (L >> 5) * 8 + (L & 7);
  int bo = (L >> 3) & 3;
  if (bm >= MB) return;
  __shared__ unsigned char sp_lds[65536];
  int tid = threadIdx.x;
  int wave = tid >> 6, lane = tid & 63;
  int q = lane >> 4, r16 = lane & 15;
  int rt0 = bm * 8 + wave * 2;
  const bf16x8* XP = (const bf16x8*)xs_pack;
  const bf16x8* BP = (const bf16x8*)bpack;

  // cooperative stage: SP slice for rows [bm*128, +128) -> LDS (64 KB)
  {
    const uint4* src = (const uint4*)((const unsigned char*)sm_pack + (size_t)bm * 65536) + tid;
    uint4* dst = (uint4*)(void*)sp_lds + tid;
#pragma unroll
    for (int it = 0; it < 16; ++it) dst[it * 256] = src[it * 256];
  }

  // C1 = xs @ W (shared across all k) — overlaps LDS staging
  f32x4 C1[2][4];
#pragma unroll
  for (int rt = 0; rt < 2; ++rt)
#pragma unroll
    for (int c = 0; c < 4; ++c) C1[rt][c] = (f32x4){0.f, 0.f, 0.f, 0.f};
#pragma unroll
  for (int kt = 0; kt < 8; ++kt) {
    bf16x8 a0 = XP[((size_t)rt0 * 8 + kt) * 64 + lane];
    bf16x8 a1 = XP[((size_t)(rt0 + 1) * 8 + kt) * 64 + lane];
#pragma unroll
    for (int c = 0; c < 4; ++c) {
      bf16x8 b = BP[((size_t)(bo * 4 + c) * 8 + kt) * 64 + lane];
      C1[0][c] = MFMA(a0, b, C1[0][c]);
      C1[1][c] = MFMA(a1, b, C1[1][c]);
    }
  }

  int row0 = bm * 128 + wave * 32 + q * 4;
  float dp[2][4];
#pragma unroll
  for (int rt = 0; rt < 2; ++rt)
#pragma unroll
    for (int rr = 0; rr < 4; ++rr) dp[rt][rr] = degp1[row0 + rt * 16 + rr];
  float bs[4];
#pragma unroll
  for (int c = 0; c < 4; ++c) bs[c] = bias[bo * 64 + c * 16 + r16];

  f32x4 outa[2][4];
#pragma unroll
  for (int rt = 0; rt < 2; ++rt)
#pragma unroll
    for (int c = 0; c < 4; ++c) outa[rt][c] = (f32x4){0.f, 0.f, 0.f, 0.f};

  __syncthreads();
  const unsigned char* myl = sp_lds + wave * 16384;

  for (int k = 0; k < KMIX; ++k) {
    float gm[2][4];
#pragma unroll
    for (int rt = 0; rt < 2; ++rt)
#pragma unroll
      for (int rr = 0; rr < 4; ++rr) gm[rt][rr] = gamma[k * Npad + row0 + rt * 16 + rr];
#pragma unroll
    for (int cp = 0; cp < 2; ++cp) {
      f32x4 ax[2][2], ac[2][2];
#pragma unroll
      for (int rt = 0; rt < 2; ++rt)
#pragma unroll
        for (int cc = 0; cc < 2; ++cc) {
          ax[rt][cc] = C1[rt][cp * 2 + cc];
          ac[rt][cc] = (f32x4){0.f, 0.f, 0.f, 0.f};
        }
      // depth-2 software pipeline over kt
      bf16x8 Bw0[8], Bw1[8], Bv0[8], Bv1[8];
#pragma unroll
      for (int kt = 0; kt < 8; ++kt) {
        if (kt == 0) {
#pragma unroll
          for (int pf = 0; pf < 2; ++pf) {
            int c0 = bo * 4 + cp * 2;
            Bw0[pf] = BP[(((size_t)(1 + k) * 16 + c0) * 8 + pf) * 64 + lane];
            Bw1[pf] = BP[(((size_t)(1 + k) * 16 + c0 + 1) * 8 + pf) * 64 + lane];
            Bv0[pf] = BP[(((size_t)(6 + k) * 16 + c0) * 8 + pf) * 64 + lane];
            Bv1[pf] = BP[(((size_t)(6 + k) * 16 + c0 + 1) * 8 + pf) * 64 + lane];
          }
        }
        if (kt < 6) {
          int pf = kt + 2;
          int c0 = bo * 4 + cp * 2;
          Bw0[pf] = BP[(((size_t)(1 + k) * 16 + c0) * 8 + pf) * 64 + lane];
          Bw1[pf] = BP[(((size_t)(1 + k) * 16 + c0 + 1) * 8 + pf) * 64 + lane];
          Bv0[pf] = BP[(((size_t)(6 + k) * 16 + c0) * 8 + pf) * 64 + lane];
          Bv1[pf] = BP[(((size_t)(6 + k) * 16 + c0 + 1) * 8 + pf) * 64 + lane];
        }
        bf16x8 sp0 = *(const bf16x8*)(myl + kt * 1024 + lane * 16);
        bf16x8 sp1 = *(const bf16x8*)(myl + 8192 + kt * 1024 + lane * 16);
        ax[0][0] = MFMA(sp0, Bw0[kt], ax[0][0]);
        ax[1][0] = MFMA(sp1, Bw0[kt], ax[1][0]);
        ac[0][0] = MFMA(sp0, Bv0[kt], ac[0][0]);
        ac[1][0] = MFMA(sp1, Bv0[kt], ac[1][0]);
        ax[0][1] = MFMA(sp0, Bw1[kt], ax[0][1]);
        ax[1][1] = MFMA(sp1, Bw1[kt], ax[1][1]);
        ac[0][1] = MFMA(sp0, Bv1[kt], ac[0][1]);
        ac[1][1] = MFMA(sp1, Bv1[kt], ac[1][1]);
      }
#pragma unroll
      for (int rt = 0; rt < 2; ++rt)
#pragma unroll
        for (int cc = 0; cc < 2; ++cc)
#pragma unroll
          for (int rr = 0; rr < 4; ++rr) {
            int c = cp * 2 + cc;
            float mu = ax[rt][cc][rr] + dp[rt][rr] * bs[c];
            float e = ex_relu_fast(mu, ac[rt][cc][rr]);
            outa[rt][c][rr] += gm[rt][rr] * e;
          }
    }
  }

  int col = bo * 64 + r16;
#pragma unroll
  for (int rt = 0; rt < 2; ++rt)
#pragma unroll
    for (int c = 0; c < 4; ++c)
#pragma unroll
      for (int rr = 0; rr < 4; ++rr) {
        int row = row0 + rt * 16 + rr;
        if (row < N) out[(long long)row * F + col + c * 16] = outa[rt][c][rr];
      }
}

extern "C" void kernel_launch(void* const* d_in, const int* in_sizes, int n_in,
                              void* d_out, int out_size, void* d_ws, size_t ws_size,
                              hipStream_t stream) {
  const float* x = (const float*)d_in[0];
  const int* edges = (const int*)d_in[1];
  const int* mask = (const int*)d_in[2];
  const float* logp = (const float*)d_in[3];
  const float* means = (const float*)d_in[4];
  const float* logvars = (const float*)d_in[5];
  const float* weight = (const float*)d_in[6];
  const float* bias = (const float*)d_in[7];
  float* out = (float*)d_out;

  int N = in_sizes[0] / F;              // 50000
  int E = in_sizes[1] / 2;              // 1600000
  int Npad = ((N + 127) / 128) * 128;   // 50048
  int MB = Npad / 128;                  // 391

  char* w = (char*)d_ws;
  auto alloc = [&](size_t bytes) {
    char* p = w;
    w += (bytes + 255) & ~(size_t)255;
    return p;
  };
  unsigned char* rec = (unsigned char*)alloc((size_t)N * RECB);
  unsigned short* xsp = (unsigned short*)alloc((size_t)Npad * F * 2);
  unsigned short* smp = (unsigned short*)alloc((size_t)Npad * F * 2);
  unsigned short* bpk = (unsigned short*)alloc((size_t)11 * F * F * 2);
  int* deg = (int*)alloc((size_t)N * 4);
  int* offs = (int*)alloc((size_t)(N + 1) * 4);
  int* cursor = (int*)alloc((size_t)N * 4);
  int* srclist = (int*)alloc((size_t)E * 4);
  float* degp1 = (float*)alloc((size_t)Npad * 4);
  float* gamma = (float*)alloc((size_t)KMIX * Npad * 4);
  float* ivar = (float*)alloc((size_t)KMIX * F * 4);

  kzero<<<196, 256, 0, stream>>>((unsigned int*)deg, N);
  k_tab<<<(KMIX * F + 255) / 256, 256, 0, stream>>>(logvars, ivar);
  k_prep<<<N, 256, 0, stream>>>(x, mask, logp, means, ivar, rec, gamma, Npad);
  k_count<<<(E + 255) / 256, 256, 0, stream>>>(edges, deg, E);
  k_scan<<<1, 1024, 0, stream>>>(deg, offs, cursor, N);
  k_fill<<<(E + 255) / 256, 256, 0, stream>>>(edges, cursor, srclist, E);
  k_gather<<<N / 16, 1024, 0, stream>>>(rec, offs, srclist, xsp, smp, degp1);
  k_bpack<<<11 * 16 * 8, 64, 0, stream>>>(weight, means, logvars, bpk);
  int NG = (MB + 7) / 8;
  k_gemm<<<NG * 32, 256, 0, stream>>>(xsp, smp, bpk, degp1, gamma, bias, out, N, Npad, MB);
}

// Round 6
// 801.509 us; speedup vs baseline: 1.2984x; 1.2984x over previous
//
#include <hip/hip_runtime.h>
#include <math.h>

#define F 256
#define KMIX 5
#define RECB 640     // node record: 512 B bf16 xm + 32 B mask bits + 96 B pad
#define GR 16        // source-node groups (L2 locality phases)
#define GS 3136      // group size: 16*3136 = 50176 >= N; 3136*640 B = 2.0 MB per group

typedef __attribute__((ext_vector_type(8))) short bf16x8;
typedef __attribute__((ext_vector_type(4))) float f32x4;

__device__ __forceinline__ float bf2f(unsigned short u) {
  union { unsigned int i; float f; } v; v.i = ((unsigned int)u) << 16; return v.f;
}
__device__ __forceinline__ unsigned short f2bf(float f) {
  union { float f; unsigned int i; } v; v.f = f;
  unsigned int u = v.i;
  unsigned int r = (u + 0x7fffu + ((u >> 16) & 1u)) >> 16;
  return (unsigned short)r;
}

__device__ __forceinline__ f32x4 MFMA(bf16x8 a, bf16x8 b, f32x4 c) {
  return __builtin_amdgcn_mfma_f32_16x16x32_bf16(a, b, c, 0, 0, 0);
}

// Fast E[relu(N(mu,sigma))]: 0.5*mu + 0.5*(mu^2+c1*sig)*rsqrt(mu^2+2*c1*sig), c1=4/pi.
// Exact at w=0 and asymptotes; max abs err ~0.025*sqrt(sig). sigma==0 -> max(mu,0).
__device__ __forceinline__ float ex_relu_fast(float mu, float sig) {
  const float c1 = 1.2732395447f;
  const float c2 = 2.5464790895f;
  float t = mu * mu;
  float u = t + c1 * sig;
  float v = t + c2 * sig + 1e-20f;
  float r = __builtin_amdgcn_rsqf(v);
  return 0.5f * mu + 0.5f * u * r;
}

__global__ void kzero(unsigned int* p, long long n) {
  long long i = (long long)blockIdx.x * blockDim.x + threadIdx.x;
  long long stride = (long long)gridDim.x * blockDim.x;
  for (; i < n; i += stride) p[i] = 0u;
}

// ivar[k][f] = exp(-logvars[k][f])
__global__ __launch_bounds__(256) void k_tab(const float* __restrict__ logvars,
                                             float* __restrict__ ivar) {
  int i = blockIdx.x * 256 + threadIdx.x;
  if (i < KMIX * F) ivar[i] = __expf(-logvars[i]);
}

// Per-node: record = [bf16 xm | bit mask], gamma = softmax_k(logp - 0.5*sum diff2)
// (reference's -0.5*F*log(2pi) and -0.5*sum(logvars) are k-independent -> cancel)
__global__ __launch_bounds__(256) void k_prep(
    const float* __restrict__ x, const int* __restrict__ mask,
    const float* __restrict__ logp, const float* __restrict__ means,
    const float* __restrict__ ivar,
    unsigned char* __restrict__ rec, float* __restrict__ gamma, int Npad) {
  int n = blockIdx.x;
  int f = threadIdx.x;
  int idx = n * F + f;
  float xv = x[idx];
  int m = mask[idx];
  unsigned char* rn = rec + (size_t)n * RECB;
  ((unsigned short*)rn)[f] = m ? (unsigned short)0 : f2bf(xv);
  int wave = threadIdx.x >> 6;
  int lane = threadIdx.x & 63;
  unsigned long long bal = __ballot(m != 0);
  if (lane == 0) *(unsigned long long*)(rn + 512 + wave * 8) = bal;
  float cb[KMIX];
#pragma unroll
  for (int k = 0; k < KMIX; ++k) {
    float d = xv - means[k * F + f];
    cb[k] = m ? 0.0f : d * d * ivar[k * F + f];
  }
  __shared__ float red[KMIX][4];
#pragma unroll
  for (int k = 0; k < KMIX; ++k) {
    float c = cb[k];
    for (int off = 32; off > 0; off >>= 1) c += __shfl_down(c, off, 64);
    if (lane == 0) red[k][wave] = c;
  }
  __syncthreads();
  if (threadIdx.x == 0) {
    float lg[KMIX], mx = -1e30f;
#pragma unroll
    for (int k = 0; k < KMIX; ++k) {
      float tot = red[k][0] + red[k][1] + red[k][2] + red[k][3];
      lg[k] = logp[k] - 0.5f * tot;
      mx = fmaxf(mx, lg[k]);
    }
    float den = 0.0f, e[KMIX];
#pragma unroll
    for (int k = 0; k < KMIX; ++k) { e[k] = __expf(lg[k] - mx); den += e[k]; }
    float inv = 1.0f / den;
#pragma unroll
    for (int k = 0; k < KMIX; ++k) gamma[k * Npad + n] = e[k] * inv;
  }
}

// count per (dst, src-group) bucket
__global__ void k_count(const int* __restrict__ edges, int* __restrict__ cnt, int E) {
  int i = blockIdx.x * blockDim.x + threadIdx.x;
  if (i < E) {
    int dst = edges[E + i];
    int g = edges[i] / GS;
    atomicAdd(&cnt[dst * GR + g], 1);
  }
}

// ---- parallel exclusive scan over n = N*GR bucket counts (3 kernels) ----
__global__ __launch_bounds__(1024) void k_scanA(const int* __restrict__ cnt,
                                                int* __restrict__ excl,
                                                int* __restrict__ bsum, int n) {
  __shared__ int s[1024];
  int t = threadIdx.x;
  int i = blockIdx.x * 1024 + t;
  int v = (i < n) ? cnt[i] : 0;
  s[t] = v;
  __syncthreads();
  for (int off = 1; off < 1024; off <<= 1) {
    int u = (t >= off) ? s[t - off] : 0;
    __syncthreads();
    s[t] += u;
    __syncthreads();
  }
  if (i < n) excl[i] = s[t] - v;
  if (t == 1023) bsum[blockIdx.x] = s[1023];
}

__global__ __launch_bounds__(1024) void k_scanB(int* __restrict__ bsum, int nb) {
  __shared__ int s[1024];
  int t = threadIdx.x;
  int v = (t < nb) ? bsum[t] : 0;
  s[t] = v;
  __syncthreads();
  for (int off = 1; off < 1024; off <<= 1) {
    int u = (t >= off) ? s[t - off] : 0;
    __syncthreads();
    s[t] += u;
    __syncthreads();
  }
  if (t < nb) bsum[t] = s[t] - v;   // exclusive block offsets
}

__global__ __launch_bounds__(1024) void k_scanC(int* __restrict__ offs,
                                                int* __restrict__ cur,
                                                const int* __restrict__ bsum,
                                                int n, int E) {
  int i = blockIdx.x * 1024 + threadIdx.x;
  if (i < n) {
    int v = offs[i] + bsum[blockIdx.x];
    offs[i] = v;
    cur[i] = v;
  }
  if (i == 0) offs[n] = E;
}

__global__ void k_fill(const int* __restrict__ edges, int* __restrict__ cur,
                       int* __restrict__ srclist, int E) {
  int i = blockIdx.x * blockDim.x + threadIdx.x;
  if (i < E) {
    int src = edges[i];
    int dst = edges[E + i];
    int g = src / GS;
    int pos = atomicAdd(&cur[dst * GR + g], 1);
    srclist[pos] = src;
  }
}

// One wave per node; 16 nodes/block. srclist is group-sorted per node, so
// concurrently-running waves sweep the 16 x 2 MB record groups in near-lockstep
// -> the hot window stays L2-resident instead of thrashing to L3.
__global__ __launch_bounds__(1024) void k_gather(
    const unsigned char* __restrict__ rec,
    const int* __restrict__ offs, const int* __restrict__ srclist,
    unsigned short* __restrict__ xs_pack, unsigned short* __restrict__ sm_pack,
    float* __restrict__ degp1) {
  __shared__ float xs_l[16][257];
  __shared__ float sm_l[16][257];
  int tile = blockIdx.x;
  int wave = threadIdx.x >> 6, lane = threadIdx.x & 63;
  int fb = lane * 4;
  int n = tile * 16 + wave;
  const unsigned char* rn = rec + (size_t)n * RECB;
  ushort4 xv = *(const ushort4*)(rn + lane * 8);
  unsigned int mw = *(const unsigned int*)(rn + 512 + ((lane >> 3) << 2));
  unsigned int nib = (mw >> ((lane & 7) * 4)) & 0xFu;
  unsigned int macc = (nib | (nib << 7) | (nib << 14) | (nib << 21)) & 0x01010101u;
  float a0 = bf2f(xv.x), a1 = bf2f(xv.y), a2 = bf2f(xv.z), a3 = bf2f(xv.w);
  int s0 = offs[n * GR], s1 = offs[n * GR + GR];   // contiguous across groups
  int i = s0;
  for (; i + 4 <= s1; i += 4) {
    int sa = srclist[i], sb = srclist[i + 1], sc = srclist[i + 2], sd = srclist[i + 3];
    const unsigned char* ra = rec + (size_t)sa * RECB;
    const unsigned char* rb = rec + (size_t)sb * RECB;
    const unsigned char* rc = rec + (size_t)sc * RECB;
    const unsigned char* rd = rec + (size_t)sd * RECB;
    ushort4 va = *(const ushort4*)(ra + lane * 8);
    ushort4 vb = *(const ushort4*)(rb + lane * 8);
    ushort4 vc = *(const ushort4*)(rc + lane * 8);
    ushort4 vd = *(const ushort4*)(rd + lane * 8);
    unsigned int wa = *(const unsigned int*)(ra + 512 + ((lane >> 3) << 2));
    unsigned int wb = *(const unsigned int*)(rb + 512 + ((lane >> 3) << 2));
    unsigned int wc = *(const unsigned int*)(rc + 512 + ((lane >> 3) << 2));
    unsigned int wd = *(const unsigned int*)(rd + 512 + ((lane >> 3) << 2));
    a0 += bf2f(va.x) + bf2f(vb.x) + bf2f(vc.x) + bf2f(vd.x);
    a1 += bf2f(va.y) + bf2f(vb.y) + bf2f(vc.y) + bf2f(vd.y);
    a2 += bf2f(va.z) + bf2f(vb.z) + bf2f(vc.z) + bf2f(vd.z);
    a3 += bf2f(va.w) + bf2f(vb.w) + bf2f(vc.w) + bf2f(vd.w);
    unsigned int na = (wa >> ((lane & 7) * 4)) & 0xFu;
    unsigned int nb = (wb >> ((lane & 7) * 4)) & 0xFu;
    unsigned int nc = (wc >> ((lane & 7) * 4)) & 0xFu;
    unsigned int nd = (wd >> ((lane & 7) * 4)) & 0xFu;
    macc += (na | (na << 7) | (na << 14) | (na << 21)) & 0x01010101u;
    macc += (nb | (nb << 7) | (nb << 14) | (nb << 21)) & 0x01010101u;
    macc += (nc | (nc << 7) | (nc << 14) | (nc << 21)) & 0x01010101u;
    macc += (nd | (nd << 7) | (nd << 14) | (nd << 21)) & 0x01010101u;
  }
  for (; i < s1; ++i) {
    int s = srclist[i];
    const unsigned char* rs = rec + (size_t)s * RECB;
    ushort4 sv = *(const ushort4*)(rs + lane * 8);
    unsigned int ws = *(const unsigned int*)(rs + 512 + ((lane >> 3) << 2));
    a0 += bf2f(sv.x); a1 += bf2f(sv.y); a2 += bf2f(sv.z); a3 += bf2f(sv.w);
    unsigned int ns = (ws >> ((lane & 7) * 4)) & 0xFu;
    macc += (ns | (ns << 7) | (ns << 14) | (ns << 21)) & 0x01010101u;
  }
  xs_l[wave][fb] = a0; xs_l[wave][fb + 1] = a1; xs_l[wave][fb + 2] = a2; xs_l[wave][fb + 3] = a3;
  sm_l[wave][fb] = (float)(macc & 0xFFu);
  sm_l[wave][fb + 1] = (float)((macc >> 8) & 0xFFu);
  sm_l[wave][fb + 2] = (float)((macc >> 16) & 0xFFu);
  sm_l[wave][fb + 3] = (float)(macc >> 24);
  if (lane == 0) degp1[n] = (float)(s1 - s0 + 1);
  __syncthreads();
  if (threadIdx.x < 512) {
    int slot = threadIdx.x;
    int kt = slot >> 6, l = slot & 63;
    int r = l & 15, q = l >> 4;
    int fbase = kt * 32 + q * 8;
    bf16x8 vx, vs;
#pragma unroll
    for (int j = 0; j < 8; ++j) {
      vx[j] = (short)f2bf(xs_l[r][fbase + j]);
      vs[j] = (short)f2bf(sm_l[r][fbase + j]);
    }
    long long po = ((long long)tile * 8 + kt) * 64 + l;
    ((bf16x8*)xs_pack)[po] = vx;
    ((bf16x8*)sm_pack)[po] = vs;
  }
}

// Pack 11 B-matrices in MFMA B-fragment order (m=0: W; 1..5: means_k*W; 6..10: var_k*W^2)
__global__ __launch_bounds__(64) void k_bpack(
    const float* __restrict__ weight, const float* __restrict__ means,
    const float* __restrict__ logvars, unsigned short* __restrict__ bpack) {
  int bid = blockIdx.x;
  int kt = bid & 7, ot = (bid >> 3) & 15, m = bid >> 7;
  int l = threadIdx.x;
  int r = l & 15, q = l >> 4;
  int o = ot * 16 + r;
  bf16x8 v;
#pragma unroll
  for (int j = 0; j < 8; ++j) {
    int f = kt * 32 + q * 8 + j;
    float wv = weight[f * F + o];
    float val;
    if (m == 0) val = wv;
    else if (m <= 5) val = means[(m - 1) * F + f] * wv;
    else val = __expf(logvars[(m - 6) * F + f]) * wv * wv;
    v[j] = (short)f2bf(val);
  }
  ((bf16x8*)bpack)[((long long)(m * 16 + ot) * 8 + kt) * 64 + l] = v;
}

// Fused GEMM + ex_relu + gamma-weighted k-reduction. Round-4 compiler-scheduled
// body (explicit prefetch regressed: VGPR spill). 1-D swizzled grid: all 4
// bo-blocks of one bm share an XCD -> A/SP slice fetched once per XCD.
__global__ __launch_bounds__(256, 2) void k_gemm(
    const unsigned short* __restrict__ xs_pack, const unsigned short* __restrict__ sm_pack,
    const unsigned short* __restrict__ bpack, const float* __restrict__ degp1,
    const float* __restrict__ gamma, const float* __restrict__ bias,
    float* __restrict__ out, int N, int Npad, int MB) {
  int L = blockIdx.x;
  int bm = (L >> 5) * 8 + (L & 7);
  int bo = (L >> 3) & 3;
  if (bm >= MB) return;
  __shared__ unsigned char sp_lds[65536];
  int tid = threadIdx.x;
  int wave = tid >> 6, lane = tid & 63;
  int q = lane >> 4, r16 = lane & 15;
  int rt0 = bm * 8 + wave * 2;
  const bf16x8* XP = (const bf16x8*)xs_pack;
  const bf16x8* BP = (const bf16x8*)bpack;

  // cooperative stage: SP slice for rows [bm*128, +128) -> LDS (64 KB)
  {
    const uint4* src = (const uint4*)((const unsigned char*)sm_pack + (size_t)bm * 65536) + tid;
    uint4* dst = (uint4*)(void*)sp_lds + tid;
#pragma unroll
    for (int it = 0; it < 16; ++it) dst[it * 256] = src[it * 256];
  }

  // C1 = xs @ W (shared across all k) — overlaps LDS staging
  f32x4 C1[2][4];
#pragma unroll
  for (int rt = 0; rt < 2; ++rt)
#pragma unroll
    for (int c = 0; c < 4; ++c) C1[rt][c] = (f32x4){0.f, 0.f, 0.f, 0.f};
#pragma unroll
  for (int kt = 0; kt < 8; ++kt) {
    bf16x8 a0 = XP[((size_t)rt0 * 8 + kt) * 64 + lane];
    bf16x8 a1 = XP[((size_t)(rt0 + 1) * 8 + kt) * 64 + lane];
#pragma unroll
    for (int c = 0; c < 4; ++c) {
      bf16x8 b = BP[((size_t)(bo * 4 + c) * 8 + kt) * 64 + lane];
      C1[0][c] = MFMA(a0, b, C1[0][c]);
      C1[1][c] = MFMA(a1, b, C1[1][c]);
    }
  }

  int row0 = bm * 128 + wave * 32 + q * 4;
  float dp[2][4];
#pragma unroll
  for (int rt = 0; rt < 2; ++rt)
#pragma unroll
    for (int rr = 0; rr < 4; ++rr) dp[rt][rr] = degp1[row0 + rt * 16 + rr];
  float bs[4];
#pragma unroll
  for (int c = 0; c < 4; ++c) bs[c] = bias[bo * 64 + c * 16 + r16];

  f32x4 outa[2][4];
#pragma unroll
  for (int rt = 0; rt < 2; ++rt)
#pragma unroll
    for (int c = 0; c < 4; ++c) outa[rt][c] = (f32x4){0.f, 0.f, 0.f, 0.f};

  __syncthreads();
  const unsigned char* myl = sp_lds + wave * 16384;

  for (int k = 0; k < KMIX; ++k) {
    float gm[2][4];
#pragma unroll
    for (int rt = 0; rt < 2; ++rt)
#pragma unroll
      for (int rr = 0; rr < 4; ++rr) gm[rt][rr] = gamma[k * Npad + row0 + rt * 16 + rr];
#pragma unroll
    for (int cp = 0; cp < 2; ++cp) {
      f32x4 ax[2][2], ac[2][2];
#pragma unroll
      for (int rt = 0; rt < 2; ++rt)
#pragma unroll
        for (int cc = 0; cc < 2; ++cc) {
          ax[rt][cc] = C1[rt][cp * 2 + cc];
          ac[rt][cc] = (f32x4){0.f, 0.f, 0.f, 0.f};
        }
#pragma unroll
      for (int kt = 0; kt < 8; ++kt) {
        bf16x8 sp0 = *(const bf16x8*)(myl + kt * 1024 + lane * 16);
        bf16x8 sp1 = *(const bf16x8*)(myl + 8192 + kt * 1024 + lane * 16);
#pragma unroll
        for (int cc = 0; cc < 2; ++cc) {
          int c = cp * 2 + cc;
          bf16x8 bw = BP[(((size_t)(1 + k) * 16 + (bo * 4 + c)) * 8 + kt) * 64 + lane];
          bf16x8 bv = BP[(((size_t)(6 + k) * 16 + (bo * 4 + c)) * 8 + kt) * 64 + lane];
          ax[0][cc] = MFMA(sp0, bw, ax[0][cc]);
          ax[1][cc] = MFMA(sp1, bw, ax[1][cc]);
          ac[0][cc] = MFMA(sp0, bv, ac[0][cc]);
          ac[1][cc] = MFMA(sp1, bv, ac[1][cc]);
        }
      }
#pragma unroll
      for (int rt = 0; rt < 2; ++rt)
#pragma unroll
        for (int cc = 0; cc < 2; ++cc)
#pragma unroll
          for (int rr = 0; rr < 4; ++rr) {
            int c = cp * 2 + cc;
            float mu = ax[rt][cc][rr] + dp[rt][rr] * bs[c];
            float e = ex_relu_fast(mu, ac[rt][cc][rr]);
            outa[rt][c][rr] += gm[rt][rr] * e;
          }
    }
  }

  int col = bo * 64 + r16;
#pragma unroll
  for (int rt = 0; rt < 2; ++rt)
#pragma unroll
    for (int c = 0; c < 4; ++c)
#pragma unroll
      for (int rr = 0; rr < 4; ++rr) {
        int row = row0 + rt * 16 + rr;
        if (row < N) out[(long long)row * F + col + c * 16] = outa[rt][c][rr];
      }
}

extern "C" void kernel_launch(void* const* d_in, const int* in_sizes, int n_in,
                              void* d_out, int out_size, void* d_ws, size_t ws_size,
                              hipStream_t stream) {
  const float* x = (const float*)d_in[0];
  const int* edges = (const int*)d_in[1];
  const int* mask = (const int*)d_in[2];
  const float* logp = (const float*)d_in[3];
  const float* means = (const float*)d_in[4];
  const float* logvars = (const float*)d_in[5];
  const float* weight = (const float*)d_in[6];
  const float* bias = (const float*)d_in[7];
  float* out = (float*)d_out;

  int N = in_sizes[0] / F;              // 50000
  int E = in_sizes[1] / 2;              // 1600000
  int Npad = ((N + 127) / 128) * 128;   // 50048
  int MB = Npad / 128;                  // 391
  int NB = N * GR;                      // bucket count
  int SB = (NB + 1023) / 1024;          // scan blocks (782 <= 1024)

  char* w = (char*)d_ws;
  auto alloc = [&](size_t bytes) {
    char* p = w;
    w += (bytes + 255) & ~(size_t)255;
    return p;
  };
  unsigned char* rec = (unsigned char*)alloc((size_t)N * RECB);
  unsigned short* xsp = (unsigned short*)alloc((size_t)Npad * F * 2);
  unsigned short* smp = (unsigned short*)alloc((size_t)Npad * F * 2);
  unsigned short* bpk = (unsigned short*)alloc((size_t)11 * F * F * 2);
  int* cnt = (int*)alloc((size_t)NB * 4);
  int* offs = (int*)alloc((size_t)(NB + 1) * 4);
  int* cur = (int*)alloc((size_t)NB * 4);
  int* bsum = (int*)alloc((size_t)1024 * 4);
  int* srclist = (int*)alloc((size_t)E * 4);
  float* degp1 = (float*)alloc((size_t)Npad * 4);
  float* gamma = (float*)alloc((size_t)KMIX * Npad * 4);
  float* ivar = (float*)alloc((size_t)KMIX * F * 4);

  kzero<<<782, 256, 0, stream>>>((unsigned int*)cnt, NB);
  k_tab<<<(KMIX * F + 255) / 256, 256, 0, stream>>>(logvars, ivar);
  k_prep<<<N, 256, 0, stream>>>(x, mask, logp, means, ivar, rec, gamma, Npad);
  k_count<<<(E + 255) / 256, 256, 0, stream>>>(edges, cnt, E);
  k_scanA<<<SB, 1024, 0, stream>>>(cnt, offs, bsum, NB);
  k_scanB<<<1, 1024, 0, stream>>>(bsum, SB);
  k_scanC<<<SB, 1024, 0, stream>>>(offs, cur, bsum, NB, E);
  k_fill<<<(E + 255) / 256, 256, 0, stream>>>(edges, cur, srclist, E);
  k_gather<<<N / 16, 1024, 0, stream>>>(rec, offs, srclist, xsp, smp, degp1);
  k_bpack<<<11 * 16 * 8, 64, 0, stream>>>(weight, means, logvars, bpk);
  int NG = (MB + 7) / 8;
  k_gemm<<<NG * 32, 256, 0, stream>>>(xsp, smp, bpk, degp1, gamma, bias, out, N, Npad, MB);
}